// Round 1
// 188.551 us; speedup vs baseline: 1.2405x; 1.2405x over previous
//
#include <hip/hip_runtime.h>

#define DD 128
#define HH 64
#define RR 4
#define NT 256          // k_dense block
#define NNT 512         // k_node block (8 waves, 128 nodes)
#define DGRID 512       // persistent k_dense blocks (2/CU exactly)
#define DPART 128       // DGRID / RR tiles-stride per relation

typedef __attribute__((ext_vector_type(8))) __bf16 bf16x8;
typedef __attribute__((ext_vector_type(4))) float f32x4;

// LDS row strides (bf16 elements). Odd multiples of 8 -> every 8-lane phase of a
// b128 read/write hits distinct bank-quads (conflict-free both directions).
#define SK128 136   // K=128 rows (+8 pad)
#define SK64  72    // K=64 rows  (+8 pad)
#define ABLK  2176  // per-wave act block: H rows (SK64) overlay low part, Ms rows (SK128)

// k_dense dynamic LDS layout (elements)
#define O_W1  0                    // 64 x 136 = 8704
#define O_W2  8704                 // 64 x 72  = 4608
#define O_W3  13312                // 128 x 72 = 9216
#define O_WP  22528                // 64 x 136 = 8704
#define O_ACT 31232                // 4 x 2176 = 8704
#define DSMEM_ELEMS 39936          // 79872 B -> 2 blocks/CU (dynamic)
// k_node dynamic LDS layout (8 waves of act)
#define N_W1  0
#define N_W2  8704
#define N_W3  13312
#define N_ACT 22528                // + 8 x 2176 = 17408
#define NSMEM_ELEMS 39936          // 79872 B -> 2 blocks/CU (16 waves/CU)

// global bf16 weight pool offsets (elements), all matrices [n][k] row-major
#define W1T_OFF 0        // [R][64][128]
#define W2T_OFF 32768    // [R][64][64]
#define W3T_OFF 49152    // [R][128][64]
#define WPT_OFF 81920    // [R][64][128]  (Wn1 slice 1+r)
#define WN1_OFF 114688   // [64][128]     (Wn1 slice 0)
#define WN2_OFF 122880   // [64][64]
#define WN3_OFF 126976   // [128][64]
#define WT_TOTAL 135168

#define MFMA(a, b, c) __builtin_amdgcn_mfma_f32_16x16x32_bf16(a, b, c, 0, 0, 0)

// Stage [ROWS][COLS] row-major global -> LDS rows with padded STRIDE.
template<int ROWS, int COLS, int STRIDE, int BLK>
__device__ __forceinline__ void stageRM(const __bf16* __restrict__ g, __bf16* s, int tid) {
    constexpr int CH = COLS / 8;
    constexpr int TOT = ROWS * CH;
    #pragma unroll
    for (int i = tid; i < TOT; i += BLK) {
        const int row = i / CH, c8 = i % CH;
        *(bf16x8*)(s + row * STRIDE + c8 * 8) = *(const bf16x8*)(g + row * COLS + c8 * 8);
    }
}

// ---------------- fused: dst histogram + weight transpose/convert ----------------
__global__ void k_prep_hist(const float* __restrict__ Wr1, const float* __restrict__ Wr2,
                            const float* __restrict__ Wr3, const float* __restrict__ Wn1,
                            const float* __restrict__ Wn2, const float* __restrict__ Wn3,
                            __bf16* __restrict__ wt,
                            const int* __restrict__ ed, int* __restrict__ dstCnt, int E) {
    int i = blockIdx.x * blockDim.x + threadIdx.x;
    if (i < E) atomicAdd(&dstCnt[ed[i]], 1);
    if (i < 32768) {                                  // Wr1 [r][k128][n64] -> W1t [r][n][k]
        int r = i >> 13, k = (i >> 6) & 127, n = i & 63;
        wt[W1T_OFF + r * 8192 + n * 128 + k] = (__bf16)Wr1[i];
    } else if (i < 49152) {                           // Wr2 [r][k64][n64]
        int j = i - 32768; int r = j >> 12, k = (j >> 6) & 63, n = j & 63;
        wt[W2T_OFF + r * 4096 + n * 64 + k] = (__bf16)Wr2[j];
    } else if (i < 81920) {                           // Wr3 [r][k64][n128]
        int j = i - 49152; int r = j >> 13, k = (j >> 7) & 63, n = j & 127;
        wt[W3T_OFF + r * 8192 + n * 64 + k] = (__bf16)Wr3[j];
    } else if (i < 122880) {                          // Wn1 [(R+1)*128][64]
        int j = i - 81920; int row = j >> 6, n = j & 63;
        int s = row >> 7, k = row & 127;
        float v = Wn1[j];
        if (s == 0) wt[WN1_OFF + n * 128 + k] = (__bf16)v;
        else        wt[WPT_OFF + (s - 1) * 8192 + n * 128 + k] = (__bf16)v;
    } else if (i < 126976) {                          // Wn2 [k64][n64]
        int j = i - 122880; int k = j >> 6, n = j & 63;
        wt[WN2_OFF + n * 64 + k] = (__bf16)Wn2[j];
    } else if (i < WT_TOTAL) {                        // Wn3 [k64][n128]
        int j = i - 126976; int k = j >> 7, n = j & 127;
        wt[WN3_OFF + n * 64 + k] = (__bf16)Wn3[j];
    }
}

// ---------------- parallel CSR scan ----------------
__global__ void k_bsum(const int* __restrict__ dstCnt, int* __restrict__ blkSum, int Nn) {
    int b = blockIdx.x, t = threadIdx.x;
    int g = b * 1024 + t * 4;
    int s = 0;
    if (g + 3 < Nn) { int4 v = *(const int4*)(dstCnt + g); s = v.x + v.y + v.z + v.w; }
    else { for (int k = 0; k < 4; k++) if (g + k < Nn) s += dstCnt[g + k]; }
    for (int off = 32; off > 0; off >>= 1) s += __shfl_down(s, off);
    __shared__ int ws[4];
    if ((t & 63) == 0) ws[t >> 6] = s;
    __syncthreads();
    if (t == 0) blkSum[b] = ws[0] + ws[1] + ws[2] + ws[3];
}

__global__ void k_mid(const int* __restrict__ blkSum, int* __restrict__ blkOff,
                      int* __restrict__ rowStart, int NB, int Nn, int E) {
    int lane = threadIdx.x;
    int s = (lane < NB) ? blkSum[lane] : 0;
    int sc = s;
    #pragma unroll
    for (int off = 1; off < 64; off <<= 1) { int u = __shfl_up(sc, off); if (lane >= off) sc += u; }
    if (lane < NB) blkOff[lane] = sc - s;
    if (lane == 0) rowStart[Nn] = E;
}

__global__ void k_wout(const int* __restrict__ dstCnt, const int* __restrict__ blkOff,
                       int* __restrict__ rowStart, int* __restrict__ dstCursor, int Nn) {
    int b = blockIdx.x, t = threadIdx.x;
    int g = b * 1024 + t * 4;
    int4 v = {0, 0, 0, 0};
    bool full = (g + 3 < Nn);
    if (full) v = *(const int4*)(dstCnt + g);
    else {
        if (g     < Nn) v.x = dstCnt[g];
        if (g + 1 < Nn) v.y = dstCnt[g + 1];
        if (g + 2 < Nn) v.z = dstCnt[g + 2];
    }
    int s = v.x + v.y + v.z + v.w;
    int lane = t & 63, wv = t >> 6;
    int sc = s;
    #pragma unroll
    for (int off = 1; off < 64; off <<= 1) { int u = __shfl_up(sc, off); if (lane >= off) sc += u; }
    __shared__ int wsum[4];
    if (lane == 63) wsum[wv] = sc;
    __syncthreads();
    int wadd = 0;
    for (int i = 0; i < wv; i++) wadd += wsum[i];
    int e0 = blkOff[b] + wadd + sc - s;
    int4 rs; rs.x = e0; rs.y = e0 + v.x; rs.z = rs.y + v.y; rs.w = rs.z + v.z;
    if (full) { *(int4*)(rowStart + g) = rs; *(int4*)(dstCursor + g) = rs; }
    else {
        int a[4] = {rs.x, rs.y, rs.z, rs.w};
        for (int k = 0; k < 4; k++) if (g + k < Nn) { rowStart[g + k] = a[k]; dstCursor[g + k] = a[k]; }
    }
}

// ---------------- CSR fill: per edge store packed (type*Nn + src) key ----------------
__global__ void k_place(const int* __restrict__ et, const int* __restrict__ ed,
                        const int* __restrict__ es, int* __restrict__ dstCursor,
                        int* __restrict__ csrKey, int E, int Nn) {
    int i = blockIdx.x * blockDim.x + threadIdx.x;
    if (i < E) {
        int sl = atomicAdd(&dstCursor[ed[i]], 1);
        csrKey[sl] = et[i] * Nn + es[i];
    }
}

// ---------------- dense message+projection: PERSISTENT blocks, weights staged once ----------------
__global__ __launch_bounds__(NT, 2) void k_dense(
    const float* __restrict__ nf,
    const float* __restrict__ br1, const float* __restrict__ br2, const float* __restrict__ br3,
    const __bf16* __restrict__ wt, __bf16* __restrict__ ca, int Nn)
{
    extern __shared__ __bf16 smem[];
    const int r    = blockIdx.x & 3;
    const int part = blockIdx.x >> 2;     // 0..DPART-1
    const int tid  = threadIdx.x;
    const int w = tid >> 6;
    const int lane = tid & 63;
    const int ln = lane & 15, qd = lane >> 4;
    const int m0 = w << 4;
    __bf16* act = smem + O_ACT + w * ABLK;

    // ---- weights staged ONCE per block (amortized over ~6 tiles)
    stageRM<64, 128, SK128, NT>(wt + W1T_OFF + r * 8192, smem + O_W1, tid);
    stageRM<64,  64, SK64 , NT>(wt + W2T_OFF + r * 4096, smem + O_W2, tid);
    stageRM<128, 64, SK64 , NT>(wt + W3T_OFF + r * 8192, smem + O_W3, tid);
    stageRM<64, 128, SK128, NT>(wt + WPT_OFF + r * 8192, smem + O_WP, tid);

    // ---- biases hoisted to registers (constant per thread across tiles)
    float bv1[4], bv2[4], bv3[8];
    #pragma unroll
    for (int nt = 0; nt < 4; nt++) {
        bv1[nt] = br1[r * HH + nt * 16 + ln];
        bv2[nt] = br2[r * HH + nt * 16 + ln];
    }
    #pragma unroll
    for (int nt = 0; nt < 8; nt++) bv3[nt] = br3[r * DD + nt * 16 + ln];

    const int T = (Nn + 63) >> 6;
    const int mx = tid >> 2, qx = tid & 3;          // X-load row/quarter (wave-local rows)
    __bf16* xr = act + (mx & 15) * SK128 + 32 * qx;

    // prefetch first tile's X into registers
    float4 xv[8];
    int t = part;
    if (t < T) {
        const int node = min(t * 64 + mx, Nn - 1);
        const float4* rp = (const float4*)(nf + (size_t)node * DD) + 8 * qx;
        #pragma unroll
        for (int j = 0; j < 8; j++) xv[j] = rp[j];
    }
    __syncthreads();   // weights ready (the only barrier)

    for (; t < T; t += DPART) {
        const int nb0 = t * 64;

        // ---- X regs -> LDS (wave-local; same-wave LDS ordering, no barrier)
        #pragma unroll
        for (int jj = 0; jj < 4; jj++) {
            float4 v0 = xv[2 * jj], v1 = xv[2 * jj + 1];
            bf16x8 p;
            p[0] = (__bf16)v0.x; p[1] = (__bf16)v0.y; p[2] = (__bf16)v0.z; p[3] = (__bf16)v0.w;
            p[4] = (__bf16)v1.x; p[5] = (__bf16)v1.y; p[6] = (__bf16)v1.z; p[7] = (__bf16)v1.w;
            *(bf16x8*)(xr + 8 * jj) = p;
        }
        bf16x8 ax[4];
        #pragma unroll
        for (int i = 0; i < 4; i++)
            ax[i] = *(const bf16x8*)(act + ln * SK128 + i * 32 + 8 * qd);

        // ---- prefetch NEXT tile's X (global loads in flight across the GEMMs)
        const int tn = t + DPART;
        if (tn < T) {
            const int node = min(tn * 64 + mx, Nn - 1);
            const float4* rp = (const float4*)(nf + (size_t)node * DD) + 8 * qx;
            #pragma unroll
            for (int j = 0; j < 8; j++) xv[j] = rp[j];
        }

        // ---- GEMM1: h1 = relu(X W1 + b1)   K=128 N=64
        {
            f32x4 c[4] = {};
            #pragma unroll
            for (int kk = 0; kk < 4; kk++)
                #pragma unroll
                for (int nt = 0; nt < 4; nt++) {
                    bf16x8 b = *(const bf16x8*)(smem + O_W1 + (nt * 16 + ln) * SK128 + kk * 32 + 8 * qd);
                    c[nt] = MFMA(ax[kk], b, c[nt]);
                }
            #pragma unroll
            for (int nt = 0; nt < 4; nt++)
                #pragma unroll
                for (int rg = 0; rg < 4; rg++) {
                    float v = c[nt][rg] + bv1[nt];
                    act[(qd * 4 + rg) * SK64 + nt * 16 + ln] = (__bf16)fmaxf(v, 0.f);  // H1
                }
        }
        // ---- GEMM2: h2 = relu(h1 W2 + b2)  K=64 (H2 overlays H1)
        {
            bf16x8 a0 = *(const bf16x8*)(act + ln * SK64 + 0 + 8 * qd);
            bf16x8 a1 = *(const bf16x8*)(act + ln * SK64 + 32 + 8 * qd);
            f32x4 c[4] = {};
            #pragma unroll
            for (int nt = 0; nt < 4; nt++) {
                bf16x8 b0 = *(const bf16x8*)(smem + O_W2 + (nt * 16 + ln) * SK64 + 0 + 8 * qd);
                bf16x8 b1 = *(const bf16x8*)(smem + O_W2 + (nt * 16 + ln) * SK64 + 32 + 8 * qd);
                c[nt] = MFMA(a0, b0, c[nt]);
                c[nt] = MFMA(a1, b1, c[nt]);
            }
            #pragma unroll
            for (int nt = 0; nt < 4; nt++)
                #pragma unroll
                for (int rg = 0; rg < 4; rg++) {
                    float v = c[nt][rg] + bv2[nt];
                    act[(qd * 4 + rg) * SK64 + nt * 16 + ln] = (__bf16)fmaxf(v, 0.f);  // H2
                }
        }
        // ---- GEMM3: msg = relu(h2 W3 + b3)  N=128 K=64 -> Ms (stride SK128)
        {
            bf16x8 a0 = *(const bf16x8*)(act + ln * SK64 + 0 + 8 * qd);
            bf16x8 a1 = *(const bf16x8*)(act + ln * SK64 + 32 + 8 * qd);
            f32x4 c[8];
            #pragma unroll
            for (int nt = 0; nt < 8; nt++) {
                bf16x8 b0 = *(const bf16x8*)(smem + O_W3 + (nt * 16 + ln) * SK64 + 0 + 8 * qd);
                bf16x8 b1 = *(const bf16x8*)(smem + O_W3 + (nt * 16 + ln) * SK64 + 32 + 8 * qd);
                f32x4 acc = {};
                acc = MFMA(a0, b0, acc);
                acc = MFMA(a1, b1, acc);
                c[nt] = acc;
            }
            #pragma unroll
            for (int nt = 0; nt < 8; nt++)
                #pragma unroll
                for (int rg = 0; rg < 4; rg++) {
                    float v = c[nt][rg] + bv3[nt];
                    act[(qd * 4 + rg) * SK128 + nt * 16 + ln] = (__bf16)fmaxf(v, 0.f);  // Ms
                }
        }
        // ---- PROJ: contrib = msg Wp_r  K=128 N=64 -> ca
        {
            bf16x8 am[4];
            #pragma unroll
            for (int i = 0; i < 4; i++)
                am[i] = *(const bf16x8*)(act + ln * SK128 + i * 32 + 8 * qd);
            f32x4 c[4] = {};
            #pragma unroll
            for (int kk = 0; kk < 4; kk++)
                #pragma unroll
                for (int nt = 0; nt < 4; nt++) {
                    bf16x8 b = *(const bf16x8*)(smem + O_WP + (nt * 16 + ln) * SK128 + kk * 32 + 8 * qd);
                    c[nt] = MFMA(am[kk], b, c[nt]);
                }
            #pragma unroll
            for (int rg = 0; rg < 4; rg++) {
                const int node = nb0 + m0 + qd * 4 + rg;
                if (node < Nn) {
                    __bf16* cp = ca + ((size_t)r * Nn + node) * HH;
                    #pragma unroll
                    for (int nt = 0; nt < 4; nt++)
                        cp[nt * 16 + ln] = (__bf16)c[nt][rg];
                }
            }
        }
    }
}

// ---------------- node updater MLP: 512-thread blocks (128 nodes), 16 waves/CU ----------------
__global__ __launch_bounds__(NNT, 4) void k_node(
    const float* __restrict__ nf,
    const float* __restrict__ bn1, const float* __restrict__ bn2, const float* __restrict__ bn3,
    const __bf16* __restrict__ wt, const __bf16* __restrict__ ca,
    const int* __restrict__ rowStart, const int* __restrict__ csrKey,
    float* __restrict__ out, int Nn)
{
    extern __shared__ __bf16 smem[];
    const int nb0 = blockIdx.x * 128;
    const int tid = threadIdx.x;
    const int w = tid >> 6;
    const int lane = tid & 63;
    const int ln = lane & 15, qd = lane >> 4;
    const int m0 = w << 4;
    __bf16* act = smem + N_ACT + w * ABLK;

    stageRM<64, 128, SK128, NNT>(wt + WN1_OFF, smem + N_W1, tid);
    stageRM<64,  64, SK64 , NNT>(wt + WN2_OFF, smem + N_W2, tid);
    stageRM<128, 64, SK64 , NNT>(wt + WN3_OFF, smem + N_W3, tid);
    {
        const int m = tid >> 2, q = tid & 3;          // 128 rows, wave-local (m>>4 == w)
        const int node = min(nb0 + m, Nn - 1);
        const float4* rp = (const float4*)(nf + (size_t)node * DD) + 8 * q;
        __bf16* xr = act + (m & 15) * SK128 + 32 * q;
        #pragma unroll
        for (int jj = 0; jj < 4; jj++) {
            float4 v0 = rp[2 * jj], v1 = rp[2 * jj + 1];
            bf16x8 p;
            p[0] = (__bf16)fmaxf(v0.x, 0.f); p[1] = (__bf16)fmaxf(v0.y, 0.f);
            p[2] = (__bf16)fmaxf(v0.z, 0.f); p[3] = (__bf16)fmaxf(v0.w, 0.f);
            p[4] = (__bf16)fmaxf(v1.x, 0.f); p[5] = (__bf16)fmaxf(v1.y, 0.f);
            p[6] = (__bf16)fmaxf(v1.z, 0.f); p[7] = (__bf16)fmaxf(v1.w, 0.f);
            *(bf16x8*)(xr + 8 * jj) = p;
        }
    }
    bf16x8 ax[4];
    #pragma unroll
    for (int i = 0; i < 4; i++)
        ax[i] = *(const bf16x8*)(act + ln * SK128 + i * 32 + 8 * qd);

    // biases hoisted (independent global loads, overlap the gather/barrier)
    float bv1[4], bv2[4], bv3[8];
    #pragma unroll
    for (int nt = 0; nt < 4; nt++) { bv1[nt] = bn1[nt * 16 + ln]; bv2[nt] = bn2[nt * 16 + ln]; }
    #pragma unroll
    for (int nt = 0; nt < 8; nt++) bv3[nt] = bn3[nt * 16 + ln];

    // CSR gather of contribs (4 independent chains), overlaps the barrier wait
    float agg[4][4] = {};
    #pragma unroll
    for (int rg = 0; rg < 4; rg++) {
        const int node = nb0 + m0 + qd * 4 + rg;
        if (node < Nn) {
            const int s0 = rowStart[node], s1 = rowStart[node + 1];
            for (int s = s0; s < s1; s++) {
                const int key = csrKey[s];
                const __bf16* cp = ca + (size_t)key * HH + ln;
                agg[rg][0] += (float)cp[0];
                agg[rg][1] += (float)cp[16];
                agg[rg][2] += (float)cp[32];
                agg[rg][3] += (float)cp[48];
            }
        }
    }
    __syncthreads();   // weights ready

    // GEMM1n: relu(relu(X) Wn1_0 + agg + bn1)  K=128 N=64
    {
        f32x4 c[4] = {};
        #pragma unroll
        for (int kk = 0; kk < 4; kk++)
            #pragma unroll
            for (int nt = 0; nt < 4; nt++) {
                bf16x8 b = *(const bf16x8*)(smem + N_W1 + (nt * 16 + ln) * SK128 + kk * 32 + 8 * qd);
                c[nt] = MFMA(ax[kk], b, c[nt]);
            }
        #pragma unroll
        for (int nt = 0; nt < 4; nt++)
            #pragma unroll
            for (int rg = 0; rg < 4; rg++) {
                float v = c[nt][rg] + bv1[nt] + agg[rg][nt];
                act[(qd * 4 + rg) * SK64 + nt * 16 + ln] = (__bf16)fmaxf(v, 0.f);
            }
    }
    // GEMM2n: K=64 (H2 overlays H1)
    {
        bf16x8 a0 = *(const bf16x8*)(act + ln * SK64 + 0 + 8 * qd);
        bf16x8 a1 = *(const bf16x8*)(act + ln * SK64 + 32 + 8 * qd);
        f32x4 c[4] = {};
        #pragma unroll
        for (int nt = 0; nt < 4; nt++) {
            bf16x8 b0 = *(const bf16x8*)(smem + N_W2 + (nt * 16 + ln) * SK64 + 0 + 8 * qd);
            bf16x8 b1 = *(const bf16x8*)(smem + N_W2 + (nt * 16 + ln) * SK64 + 32 + 8 * qd);
            c[nt] = MFMA(a0, b0, c[nt]);
            c[nt] = MFMA(a1, b1, c[nt]);
        }
        #pragma unroll
        for (int nt = 0; nt < 4; nt++)
            #pragma unroll
            for (int rg = 0; rg < 4; rg++) {
                float v = c[nt][rg] + bv2[nt];
                act[(qd * 4 + rg) * SK64 + nt * 16 + ln] = (__bf16)fmaxf(v, 0.f);
            }
    }
    // GEMM3n: K=64 N=128 -> out (+bn3, no relu)
    {
        bf16x8 a0 = *(const bf16x8*)(act + ln * SK64 + 0 + 8 * qd);
        bf16x8 a1 = *(const bf16x8*)(act + ln * SK64 + 32 + 8 * qd);
        f32x4 c[8];
        #pragma unroll
        for (int nt = 0; nt < 8; nt++) {
            bf16x8 b0 = *(const bf16x8*)(smem + N_W3 + (nt * 16 + ln) * SK64 + 0 + 8 * qd);
            bf16x8 b1 = *(const bf16x8*)(smem + N_W3 + (nt * 16 + ln) * SK64 + 32 + 8 * qd);
            f32x4 acc = {};
            acc = MFMA(a0, b0, acc);
            acc = MFMA(a1, b1, acc);
            c[nt] = acc;
        }
        #pragma unroll
        for (int rg = 0; rg < 4; rg++) {
            const int node = nb0 + m0 + qd * 4 + rg;
            if (node < Nn) {
                float* op = out + (size_t)node * DD;
                #pragma unroll
                for (int nt = 0; nt < 8; nt++)
                    op[nt * 16 + ln] = c[nt][rg] + bv3[nt];
            }
        }
    }
}

extern "C" void kernel_launch(void* const* d_in, const int* in_sizes, int n_in,
                              void* d_out, int out_size, void* d_ws, size_t ws_size,
                              hipStream_t stream) {
    const float* nf  = (const float*)d_in[0];
    const int*   es  = (const int*)d_in[1];
    const int*   ed  = (const int*)d_in[2];
    const int*   et  = (const int*)d_in[3];
    const float* Wr1 = (const float*)d_in[4];
    const float* br1 = (const float*)d_in[5];
    const float* Wr2 = (const float*)d_in[6];
    const float* br2 = (const float*)d_in[7];
    const float* Wr3 = (const float*)d_in[8];
    const float* br3 = (const float*)d_in[9];
    const float* Wn1 = (const float*)d_in[10];
    const float* bn1 = (const float*)d_in[11];
    const float* Wn2 = (const float*)d_in[12];
    const float* bn2 = (const float*)d_in[13];
    const float* Wn3 = (const float*)d_in[14];
    const float* bn3 = (const float*)d_in[15];
    float* out = (float*)d_out;

    const int Nn = in_sizes[0] / DD;   // 50000
    const int E  = in_sizes[1];        // 200000
    const int NB = (Nn + 1023) / 1024; // <=64

    int* p = (int*)d_ws;
    int* dstCnt    = p;                 p += Nn;      // zeroed
    int* dstCursor = p;                 p += Nn;
    int* rowStart  = p;                 p += Nn + 1;
    int* blkSum    = p;                 p += 64;
    int* blkOff    = p;                 p += 64;
    int* csrKey    = p;                 p += E;
    p += ((8 - ((p - (int*)d_ws) & 7)) & 7);          // 32B-align
    __bf16* wbf = (__bf16*)p;           p += (WT_TOTAL + 1) / 2;
    __bf16* ca  = (__bf16*)p;                          // RR*Nn*HH bf16 = 25.6 MB

    hipFuncSetAttribute((const void*)k_dense,
                        hipFuncAttributeMaxDynamicSharedMemorySize,
                        DSMEM_ELEMS * (int)sizeof(__bf16));
    hipFuncSetAttribute((const void*)k_node,
                        hipFuncAttributeMaxDynamicSharedMemorySize,
                        NSMEM_ELEMS * (int)sizeof(__bf16));

    hipMemsetAsync((void*)dstCnt, 0, (size_t)Nn * sizeof(int), stream);

    const int nb = (E + NT - 1) / NT;
    k_prep_hist<<<nb, NT, 0, stream>>>(Wr1, Wr2, Wr3, Wn1, Wn2, Wn3, wbf, ed, dstCnt, E);
    k_bsum <<<NB, 256, 0, stream>>>(dstCnt, blkSum, Nn);
    k_mid  <<<1, 64, 0, stream>>>(blkSum, blkOff, rowStart, NB, Nn, E);
    k_wout <<<NB, 256, 0, stream>>>(dstCnt, blkOff, rowStart, dstCursor, Nn);
    k_place<<<nb, NT, 0, stream>>>(et, ed, es, dstCursor, csrKey, E, Nn);

    k_dense<<<DGRID, NT, DSMEM_ELEMS * sizeof(__bf16), stream>>>(nf, br1, br2, br3, wbf, ca, Nn);
    k_node <<<(Nn + 127) / 128, NNT, NSMEM_ELEMS * sizeof(__bf16), stream>>>(
        nf, bn1, bn2, bn3, wbf, ca, rowStart, csrKey, out, Nn);
}

// Round 3
// 183.378 us; speedup vs baseline: 1.2755x; 1.0282x over previous
//
#include <hip/hip_runtime.h>

#define DD 128
#define HH 64
#define RR 4
#define NT 256          // k_dense block
#define NNT 512         // k_node block (8 waves, 128 nodes)
#define DGRID 512       // persistent k_dense blocks (2/CU exactly)
#define DPART 128       // DGRID / RR tiles-stride per relation

typedef __attribute__((ext_vector_type(8))) __bf16 bf16x8;
typedef __attribute__((ext_vector_type(4))) __bf16 bf16x4;
typedef __attribute__((ext_vector_type(4))) float f32x4;

// LDS row strides (bf16 elements). Odd multiples of 8 -> every 8-lane phase of a
// b128 read/write hits distinct bank-quads (conflict-free both directions).
#define SK128 136   // K=128 rows (+8 pad)
#define SK64  72    // K=64 rows  (+8 pad)
#define ABLK  2176  // per-wave act block: H rows (SK64) overlay low part, Ms rows (SK128)

// k_dense dynamic LDS layout (elements)
#define O_W1  0                    // 64 x 136 = 8704
#define O_W2  8704                 // 64 x 72  = 4608
#define O_W3  13312                // 128 x 72 = 9216
#define O_WP  22528                // 64 x 136 = 8704
#define O_ACT 31232                // 4 x 2176 = 8704
#define DSMEM_ELEMS 39936          // 79872 B -> 2 blocks/CU (dynamic)
// k_node dynamic LDS layout (8 waves of act)
#define N_W1  0
#define N_W2  8704
#define N_W3  13312
#define N_ACT 22528                // + 8 x 2176 = 17408
#define NSMEM_ELEMS 39936          // 79872 B -> 2 blocks/CU (16 waves/CU)

// global bf16 weight pool offsets (elements), all matrices [n][k] row-major
#define W1T_OFF 0        // [R][64][128]
#define W2T_OFF 32768    // [R][64][64]
#define W3T_OFF 49152    // [R][128][64]
#define WPT_OFF 81920    // [R][64][128]  (Wn1 slice 1+r)
#define WN1_OFF 114688   // [64][128]     (Wn1 slice 0)
#define WN2_OFF 122880   // [64][64]
#define WN3_OFF 126976   // [128][64]
#define WT_TOTAL 135168

#define MFMA(a, b, c) __builtin_amdgcn_mfma_f32_16x16x32_bf16(a, b, c, 0, 0, 0)

// ca column permutation: stored col' = ln*4 + nt  (ln in [0,16), nt in [0,4)).
// -> k_dense PROJ writes one contiguous bf16x4 (8B) per (lane,node);
// -> k_node gather reads one contiguous bf16x4 (8B) per (lane,edge).

// Stage [ROWS][COLS] row-major global -> LDS rows with padded STRIDE.
template<int ROWS, int COLS, int STRIDE, int BLK>
__device__ __forceinline__ void stageRM(const __bf16* __restrict__ g, __bf16* s, int tid) {
    constexpr int CH = COLS / 8;
    constexpr int TOT = ROWS * CH;
    #pragma unroll
    for (int i = tid; i < TOT; i += BLK) {
        const int row = i / CH, c8 = i % CH;
        *(bf16x8*)(s + row * STRIDE + c8 * 8) = *(const bf16x8*)(g + row * COLS + c8 * 8);
    }
}

// ---------------- fused: dst histogram + weight transpose/convert ----------------
__global__ void k_prep_hist(const float* __restrict__ Wr1, const float* __restrict__ Wr2,
                            const float* __restrict__ Wr3, const float* __restrict__ Wn1,
                            const float* __restrict__ Wn2, const float* __restrict__ Wn3,
                            __bf16* __restrict__ wt,
                            const int* __restrict__ ed, int* __restrict__ dstCnt, int E) {
    int i = blockIdx.x * blockDim.x + threadIdx.x;
    if (i < E) atomicAdd(&dstCnt[ed[i]], 1);
    if (i < 32768) {                                  // Wr1 [r][k128][n64] -> W1t [r][n][k]
        int r = i >> 13, k = (i >> 6) & 127, n = i & 63;
        wt[W1T_OFF + r * 8192 + n * 128 + k] = (__bf16)Wr1[i];
    } else if (i < 49152) {                           // Wr2 [r][k64][n64]
        int j = i - 32768; int r = j >> 12, k = (j >> 6) & 63, n = j & 63;
        wt[W2T_OFF + r * 4096 + n * 64 + k] = (__bf16)Wr2[j];
    } else if (i < 81920) {                           // Wr3 [r][k64][n128]
        int j = i - 49152; int r = j >> 13, k = (j >> 7) & 63, n = j & 127;
        wt[W3T_OFF + r * 8192 + n * 64 + k] = (__bf16)Wr3[j];
    } else if (i < 122880) {                          // Wn1 [(R+1)*128][64]
        int j = i - 81920; int row = j >> 6, n = j & 63;
        int s = row >> 7, k = row & 127;
        float v = Wn1[j];
        if (s == 0) wt[WN1_OFF + n * 128 + k] = (__bf16)v;
        else        wt[WPT_OFF + (s - 1) * 8192 + n * 128 + k] = (__bf16)v;
    } else if (i < 126976) {                          // Wn2 [k64][n64]
        int j = i - 122880; int k = j >> 6, n = j & 63;
        wt[WN2_OFF + n * 64 + k] = (__bf16)Wn2[j];
    } else if (i < WT_TOTAL) {                        // Wn3 [k64][n128]
        int j = i - 126976; int k = j >> 7, n = j & 127;
        wt[WN3_OFF + n * 64 + k] = (__bf16)Wn3[j];
    }
}

// ---------------- parallel CSR scan ----------------
__global__ void k_bsum(const int* __restrict__ dstCnt, int* __restrict__ blkSum, int Nn) {
    int b = blockIdx.x, t = threadIdx.x;
    int g = b * 1024 + t * 4;
    int s = 0;
    if (g + 3 < Nn) { int4 v = *(const int4*)(dstCnt + g); s = v.x + v.y + v.z + v.w; }
    else { for (int k = 0; k < 4; k++) if (g + k < Nn) s += dstCnt[g + k]; }
    for (int off = 32; off > 0; off >>= 1) s += __shfl_down(s, off);
    __shared__ int ws[4];
    if ((t & 63) == 0) ws[t >> 6] = s;
    __syncthreads();
    if (t == 0) blkSum[b] = ws[0] + ws[1] + ws[2] + ws[3];
}

__global__ void k_mid(const int* __restrict__ blkSum, int* __restrict__ blkOff,
                      int* __restrict__ rowStart, int NB, int Nn, int E) {
    int lane = threadIdx.x;
    int s = (lane < NB) ? blkSum[lane] : 0;
    int sc = s;
    #pragma unroll
    for (int off = 1; off < 64; off <<= 1) { int u = __shfl_up(sc, off); if (lane >= off) sc += u; }
    if (lane < NB) blkOff[lane] = sc - s;
    if (lane == 0) rowStart[Nn] = E;
}

__global__ void k_wout(const int* __restrict__ dstCnt, const int* __restrict__ blkOff,
                       int* __restrict__ rowStart, int* __restrict__ dstCursor, int Nn) {
    int b = blockIdx.x, t = threadIdx.x;
    int g = b * 1024 + t * 4;
    int4 v = {0, 0, 0, 0};
    bool full = (g + 3 < Nn);
    if (full) v = *(const int4*)(dstCnt + g);
    else {
        if (g     < Nn) v.x = dstCnt[g];
        if (g + 1 < Nn) v.y = dstCnt[g + 1];
        if (g + 2 < Nn) v.z = dstCnt[g + 2];
    }
    int s = v.x + v.y + v.z + v.w;
    int lane = t & 63, wv = t >> 6;
    int sc = s;
    #pragma unroll
    for (int off = 1; off < 64; off <<= 1) { int u = __shfl_up(sc, off); if (lane >= off) sc += u; }
    __shared__ int wsum[4];
    if (lane == 63) wsum[wv] = sc;
    __syncthreads();
    int wadd = 0;
    for (int i = 0; i < wv; i++) wadd += wsum[i];
    int e0 = blkOff[b] + wadd + sc - s;
    int4 rs; rs.x = e0; rs.y = e0 + v.x; rs.z = rs.y + v.y; rs.w = rs.z + v.z;
    if (full) { *(int4*)(rowStart + g) = rs; *(int4*)(dstCursor + g) = rs; }
    else {
        int a[4] = {rs.x, rs.y, rs.z, rs.w};
        for (int k = 0; k < 4; k++) if (g + k < Nn) { rowStart[g + k] = a[k]; dstCursor[g + k] = a[k]; }
    }
}

// ---------------- CSR fill: per edge store packed (type*Nn + src) key ----------------
__global__ void k_place(const int* __restrict__ et, const int* __restrict__ ed,
                        const int* __restrict__ es, int* __restrict__ dstCursor,
                        int* __restrict__ csrKey, int E, int Nn) {
    int i = blockIdx.x * blockDim.x + threadIdx.x;
    if (i < E) {
        int sl = atomicAdd(&dstCursor[ed[i]], 1);
        csrKey[sl] = et[i] * Nn + es[i];
    }
}

// ---------------- dense message+projection: PERSISTENT blocks, weights staged once ----------------
__global__ __launch_bounds__(NT, 2) void k_dense(
    const float* __restrict__ nf,
    const float* __restrict__ br1, const float* __restrict__ br2, const float* __restrict__ br3,
    const __bf16* __restrict__ wt, __bf16* __restrict__ ca, int Nn)
{
    extern __shared__ __bf16 smem[];
    const int r    = blockIdx.x & 3;
    const int part = blockIdx.x >> 2;     // 0..DPART-1
    const int tid  = threadIdx.x;
    const int w = tid >> 6;
    const int lane = tid & 63;
    const int ln = lane & 15, qd = lane >> 4;
    const int m0 = w << 4;
    __bf16* act = smem + O_ACT + w * ABLK;

    // ---- weights staged ONCE per block (amortized over ~6 tiles)
    stageRM<64, 128, SK128, NT>(wt + W1T_OFF + r * 8192, smem + O_W1, tid);
    stageRM<64,  64, SK64 , NT>(wt + W2T_OFF + r * 4096, smem + O_W2, tid);
    stageRM<128, 64, SK64 , NT>(wt + W3T_OFF + r * 8192, smem + O_W3, tid);
    stageRM<64, 128, SK128, NT>(wt + WPT_OFF + r * 8192, smem + O_WP, tid);

    // ---- biases hoisted to registers (constant per thread across tiles)
    float bv1[4], bv2[4], bv3[8];
    #pragma unroll
    for (int nt = 0; nt < 4; nt++) {
        bv1[nt] = br1[r * HH + nt * 16 + ln];
        bv2[nt] = br2[r * HH + nt * 16 + ln];
    }
    #pragma unroll
    for (int nt = 0; nt < 8; nt++) bv3[nt] = br3[r * DD + nt * 16 + ln];

    const int T = (Nn + 63) >> 6;
    const int mx = tid >> 2, qx = tid & 3;          // X-load row/quarter (wave-local rows)
    __bf16* xr = act + (mx & 15) * SK128 + 32 * qx;

    // prefetch first tile's X into registers
    float4 xv[8];
    int t = part;
    if (t < T) {
        const int node = min(t * 64 + mx, Nn - 1);
        const float4* rp = (const float4*)(nf + (size_t)node * DD) + 8 * qx;
        #pragma unroll
        for (int j = 0; j < 8; j++) xv[j] = rp[j];
    }
    __syncthreads();   // weights ready (the only barrier)

    for (; t < T; t += DPART) {
        const int nb0 = t * 64;

        // ---- X regs -> LDS (wave-local; same-wave LDS ordering, no barrier)
        #pragma unroll
        for (int jj = 0; jj < 4; jj++) {
            float4 v0 = xv[2 * jj], v1 = xv[2 * jj + 1];
            bf16x8 p;
            p[0] = (__bf16)v0.x; p[1] = (__bf16)v0.y; p[2] = (__bf16)v0.z; p[3] = (__bf16)v0.w;
            p[4] = (__bf16)v1.x; p[5] = (__bf16)v1.y; p[6] = (__bf16)v1.z; p[7] = (__bf16)v1.w;
            *(bf16x8*)(xr + 8 * jj) = p;
        }
        bf16x8 ax[4];
        #pragma unroll
        for (int i = 0; i < 4; i++)
            ax[i] = *(const bf16x8*)(act + ln * SK128 + i * 32 + 8 * qd);

        // ---- prefetch NEXT tile's X (global loads in flight across the GEMMs)
        const int tn = t + DPART;
        if (tn < T) {
            const int node = min(tn * 64 + mx, Nn - 1);
            const float4* rp = (const float4*)(nf + (size_t)node * DD) + 8 * qx;
            #pragma unroll
            for (int j = 0; j < 8; j++) xv[j] = rp[j];
        }

        // ---- GEMM1: h1 = relu(X W1 + b1)   K=128 N=64
        {
            f32x4 c[4] = {};
            #pragma unroll
            for (int kk = 0; kk < 4; kk++)
                #pragma unroll
                for (int nt = 0; nt < 4; nt++) {
                    bf16x8 b = *(const bf16x8*)(smem + O_W1 + (nt * 16 + ln) * SK128 + kk * 32 + 8 * qd);
                    c[nt] = MFMA(ax[kk], b, c[nt]);
                }
            #pragma unroll
            for (int nt = 0; nt < 4; nt++)
                #pragma unroll
                for (int rg = 0; rg < 4; rg++) {
                    float v = c[nt][rg] + bv1[nt];
                    act[(qd * 4 + rg) * SK64 + nt * 16 + ln] = (__bf16)fmaxf(v, 0.f);  // H1
                }
        }
        // ---- GEMM2: h2 = relu(h1 W2 + b2)  K=64 (H2 overlays H1)
        {
            bf16x8 a0 = *(const bf16x8*)(act + ln * SK64 + 0 + 8 * qd);
            bf16x8 a1 = *(const bf16x8*)(act + ln * SK64 + 32 + 8 * qd);
            f32x4 c[4] = {};
            #pragma unroll
            for (int nt = 0; nt < 4; nt++) {
                bf16x8 b0 = *(const bf16x8*)(smem + O_W2 + (nt * 16 + ln) * SK64 + 0 + 8 * qd);
                bf16x8 b1 = *(const bf16x8*)(smem + O_W2 + (nt * 16 + ln) * SK64 + 32 + 8 * qd);
                c[nt] = MFMA(a0, b0, c[nt]);
                c[nt] = MFMA(a1, b1, c[nt]);
            }
            #pragma unroll
            for (int nt = 0; nt < 4; nt++)
                #pragma unroll
                for (int rg = 0; rg < 4; rg++) {
                    float v = c[nt][rg] + bv2[nt];
                    act[(qd * 4 + rg) * SK64 + nt * 16 + ln] = (__bf16)fmaxf(v, 0.f);  // H2
                }
        }
        // ---- GEMM3: msg = relu(h2 W3 + b3)  N=128 K=64 -> Ms (stride SK128)
        {
            bf16x8 a0 = *(const bf16x8*)(act + ln * SK64 + 0 + 8 * qd);
            bf16x8 a1 = *(const bf16x8*)(act + ln * SK64 + 32 + 8 * qd);
            f32x4 c[8];
            #pragma unroll
            for (int nt = 0; nt < 8; nt++) {
                bf16x8 b0 = *(const bf16x8*)(smem + O_W3 + (nt * 16 + ln) * SK64 + 0 + 8 * qd);
                bf16x8 b1 = *(const bf16x8*)(smem + O_W3 + (nt * 16 + ln) * SK64 + 32 + 8 * qd);
                f32x4 acc = {};
                acc = MFMA(a0, b0, acc);
                acc = MFMA(a1, b1, acc);
                c[nt] = acc;
            }
            #pragma unroll
            for (int nt = 0; nt < 8; nt++)
                #pragma unroll
                for (int rg = 0; rg < 4; rg++) {
                    float v = c[nt][rg] + bv3[nt];
                    act[(qd * 4 + rg) * SK128 + nt * 16 + ln] = (__bf16)fmaxf(v, 0.f);  // Ms
                }
        }
        // ---- PROJ: contrib = msg Wp_r  K=128 N=64 -> ca (permuted col: ln*4+nt, 8B stores)
        {
            bf16x8 am[4];
            #pragma unroll
            for (int i = 0; i < 4; i++)
                am[i] = *(const bf16x8*)(act + ln * SK128 + i * 32 + 8 * qd);
            f32x4 c[4] = {};
            #pragma unroll
            for (int kk = 0; kk < 4; kk++)
                #pragma unroll
                for (int nt = 0; nt < 4; nt++) {
                    bf16x8 b = *(const bf16x8*)(smem + O_WP + (nt * 16 + ln) * SK128 + kk * 32 + 8 * qd);
                    c[nt] = MFMA(am[kk], b, c[nt]);
                }
            #pragma unroll
            for (int rg = 0; rg < 4; rg++) {
                const int node = nb0 + m0 + qd * 4 + rg;
                if (node < Nn) {
                    bf16x4 v;
                    v[0] = (__bf16)c[0][rg]; v[1] = (__bf16)c[1][rg];
                    v[2] = (__bf16)c[2][rg]; v[3] = (__bf16)c[3][rg];
                    *(bf16x4*)(ca + ((size_t)r * Nn + node) * HH + ln * 4) = v;
                }
            }
        }
    }
}

// ---------------- node updater MLP: 512-thread blocks; ILP-restructured CSR gather ----------------
__global__ __launch_bounds__(NNT, 4) void k_node(
    const float* __restrict__ nf,
    const float* __restrict__ bn1, const float* __restrict__ bn2, const float* __restrict__ bn3,
    const __bf16* __restrict__ wt, const __bf16* __restrict__ ca,
    const int* __restrict__ rowStart, const int* __restrict__ csrKey,
    float* __restrict__ out, int Nn)
{
    extern __shared__ __bf16 smem[];
    const int nb0 = blockIdx.x * 128;
    const int tid = threadIdx.x;
    const int w = tid >> 6;
    const int lane = tid & 63;
    const int ln = lane & 15, qd = lane >> 4;
    const int m0 = w << 4;
    __bf16* act = smem + N_ACT + w * ABLK;

    stageRM<64, 128, SK128, NNT>(wt + WN1_OFF, smem + N_W1, tid);
    stageRM<64,  64, SK64 , NNT>(wt + WN2_OFF, smem + N_W2, tid);
    stageRM<128, 64, SK64 , NNT>(wt + WN3_OFF, smem + N_W3, tid);
    {
        const int m = tid >> 2, q = tid & 3;          // 128 rows, wave-local (m>>4 == w)
        const int node = min(nb0 + m, Nn - 1);
        const float4* rp = (const float4*)(nf + (size_t)node * DD) + 8 * q;
        __bf16* xr = act + (m & 15) * SK128 + 32 * q;
        #pragma unroll
        for (int jj = 0; jj < 4; jj++) {
            float4 v0 = rp[2 * jj], v1 = rp[2 * jj + 1];
            bf16x8 p;
            p[0] = (__bf16)fmaxf(v0.x, 0.f); p[1] = (__bf16)fmaxf(v0.y, 0.f);
            p[2] = (__bf16)fmaxf(v0.z, 0.f); p[3] = (__bf16)fmaxf(v0.w, 0.f);
            p[4] = (__bf16)fmaxf(v1.x, 0.f); p[5] = (__bf16)fmaxf(v1.y, 0.f);
            p[6] = (__bf16)fmaxf(v1.z, 0.f); p[7] = (__bf16)fmaxf(v1.w, 0.f);
            *(bf16x8*)(xr + 8 * jj) = p;
        }
    }
    bf16x8 ax[4];
    #pragma unroll
    for (int i = 0; i < 4; i++)
        ax[i] = *(const bf16x8*)(act + ln * SK128 + i * 32 + 8 * qd);

    // biases hoisted (independent global loads, overlap the gather/barrier)
    float bv1[4], bv2[4], bv3[8];
    #pragma unroll
    for (int nt = 0; nt < 4; nt++) { bv1[nt] = bn1[nt * 16 + ln]; bv2[nt] = bn2[nt * 16 + ln]; }
    #pragma unroll
    for (int nt = 0; nt < 8; nt++) bv3[nt] = bn3[nt * 16 + ln];

    // ---- CSR gather, permuted ca layout: one bf16x4 (8B) per (lane, edge).
    // 4 rows interleaved + 2-edge unroll -> up to 8 key loads then 8 data loads in flight.
    float agg[4][4] = {};
    {
        const int base = nb0 + m0 + qd * 4;           // 4 consecutive node rows
        int rs[5];
        #pragma unroll
        for (int j = 0; j < 5; j++) rs[j] = rowStart[min(base + j, Nn)];
        int cur[4];
        #pragma unroll
        for (int rg = 0; rg < 4; rg++) cur[rg] = rs[rg];
        const __bf16* cab = ca + ln * 4;

        while (true) {
            int k0[4], k1[4];
            bool v0[4], v1[4];
            bool any = false;
            #pragma unroll
            for (int rg = 0; rg < 4; rg++) {
                const int c0 = cur[rg], e1 = rs[rg + 1];
                v0[rg] = c0 < e1;
                v1[rg] = c0 + 1 < e1;
                if (v0[rg]) k0[rg] = csrKey[c0];
                if (v1[rg]) k1[rg] = csrKey[c0 + 1];
                cur[rg] = c0 + (v0[rg] ? 1 : 0) + (v1[rg] ? 1 : 0);
                any |= v0[rg];
            }
            if (!any) break;
            #pragma unroll
            for (int rg = 0; rg < 4; rg++) {
                if (v0[rg]) {
                    const bf16x4 x = *(const bf16x4*)(cab + (size_t)k0[rg] * HH);
                    agg[rg][0] += (float)x[0]; agg[rg][1] += (float)x[1];
                    agg[rg][2] += (float)x[2]; agg[rg][3] += (float)x[3];
                }
                if (v1[rg]) {
                    const bf16x4 x = *(const bf16x4*)(cab + (size_t)k1[rg] * HH);
                    agg[rg][0] += (float)x[0]; agg[rg][1] += (float)x[1];
                    agg[rg][2] += (float)x[2]; agg[rg][3] += (float)x[3];
                }
            }
        }
    }
    __syncthreads();   // weights ready

    // GEMM1n: relu(relu(X) Wn1_0 + agg + bn1)  K=128 N=64
    {
        f32x4 c[4] = {};
        #pragma unroll
        for (int kk = 0; kk < 4; kk++)
            #pragma unroll
            for (int nt = 0; nt < 4; nt++) {
                bf16x8 b = *(const bf16x8*)(smem + N_W1 + (nt * 16 + ln) * SK128 + kk * 32 + 8 * qd);
                c[nt] = MFMA(ax[kk], b, c[nt]);
            }
        #pragma unroll
        for (int nt = 0; nt < 4; nt++)
            #pragma unroll
            for (int rg = 0; rg < 4; rg++) {
                float v = c[nt][rg] + bv1[nt] + agg[rg][nt];
                act[(qd * 4 + rg) * SK64 + nt * 16 + ln] = (__bf16)fmaxf(v, 0.f);
            }
    }
    // GEMM2n: K=64 (H2 overlays H1)
    {
        bf16x8 a0 = *(const bf16x8*)(act + ln * SK64 + 0 + 8 * qd);
        bf16x8 a1 = *(const bf16x8*)(act + ln * SK64 + 32 + 8 * qd);
        f32x4 c[4] = {};
        #pragma unroll
        for (int nt = 0; nt < 4; nt++) {
            bf16x8 b0 = *(const bf16x8*)(smem + N_W2 + (nt * 16 + ln) * SK64 + 0 + 8 * qd);
            bf16x8 b1 = *(const bf16x8*)(smem + N_W2 + (nt * 16 + ln) * SK64 + 32 + 8 * qd);
            c[nt] = MFMA(a0, b0, c[nt]);
            c[nt] = MFMA(a1, b1, c[nt]);
        }
        #pragma unroll
        for (int nt = 0; nt < 4; nt++)
            #pragma unroll
            for (int rg = 0; rg < 4; rg++) {
                float v = c[nt][rg] + bv2[nt];
                act[(qd * 4 + rg) * SK64 + nt * 16 + ln] = (__bf16)fmaxf(v, 0.f);
            }
    }
    // GEMM3n: K=64 N=128 -> out (+bn3, no relu)
    {
        bf16x8 a0 = *(const bf16x8*)(act + ln * SK64 + 0 + 8 * qd);
        bf16x8 a1 = *(const bf16x8*)(act + ln * SK64 + 32 + 8 * qd);
        f32x4 c[8];
        #pragma unroll
        for (int nt = 0; nt < 8; nt++) {
            bf16x8 b0 = *(const bf16x8*)(smem + N_W3 + (nt * 16 + ln) * SK64 + 0 + 8 * qd);
            bf16x8 b1 = *(const bf16x8*)(smem + N_W3 + (nt * 16 + ln) * SK64 + 32 + 8 * qd);
            f32x4 acc = {};
            acc = MFMA(a0, b0, acc);
            acc = MFMA(a1, b1, acc);
            c[nt] = acc;
        }
        #pragma unroll
        for (int rg = 0; rg < 4; rg++) {
            const int node = nb0 + m0 + qd * 4 + rg;
            if (node < Nn) {
                float* op = out + (size_t)node * DD;
                #pragma unroll
                for (int nt = 0; nt < 8; nt++)
                    op[nt * 16 + ln] = c[nt][rg] + bv3[nt];
            }
        }
    }
}

extern "C" void kernel_launch(void* const* d_in, const int* in_sizes, int n_in,
                              void* d_out, int out_size, void* d_ws, size_t ws_size,
                              hipStream_t stream) {
    const float* nf  = (const float*)d_in[0];
    const int*   es  = (const int*)d_in[1];
    const int*   ed  = (const int*)d_in[2];
    const int*   et  = (const int*)d_in[3];
    const float* Wr1 = (const float*)d_in[4];
    const float* br1 = (const float*)d_in[5];
    const float* Wr2 = (const float*)d_in[6];
    const float* br2 = (const float*)d_in[7];
    const float* Wr3 = (const float*)d_in[8];
    const float* br3 = (const float*)d_in[9];
    const float* Wn1 = (const float*)d_in[10];
    const float* bn1 = (const float*)d_in[11];
    const float* Wn2 = (const float*)d_in[12];
    const float* bn2 = (const float*)d_in[13];
    const float* Wn3 = (const float*)d_in[14];
    const float* bn3 = (const float*)d_in[15];
    float* out = (float*)d_out;

    const int Nn = in_sizes[0] / DD;   // 50000
    const int E  = in_sizes[1];        // 200000
    const int NB = (Nn + 1023) / 1024; // <=64

    int* p = (int*)d_ws;
    int* dstCnt    = p;                 p += Nn;      // zeroed
    int* dstCursor = p;                 p += Nn;
    int* rowStart  = p;                 p += Nn + 1;
    int* blkSum    = p;                 p += 64;
    int* blkOff    = p;                 p += 64;
    int* csrKey    = p;                 p += E;
    p += ((8 - ((p - (int*)d_ws) & 7)) & 7);          // 32B-align
    __bf16* wbf = (__bf16*)p;           p += (WT_TOTAL + 1) / 2;
    __bf16* ca  = (__bf16*)p;                          // RR*Nn*HH bf16 = 25.6 MB

    hipFuncSetAttribute((const void*)k_dense,
                        hipFuncAttributeMaxDynamicSharedMemorySize,
                        DSMEM_ELEMS * (int)sizeof(__bf16));
    hipFuncSetAttribute((const void*)k_node,
                        hipFuncAttributeMaxDynamicSharedMemorySize,
                        NSMEM_ELEMS * (int)sizeof(__bf16));

    hipMemsetAsync((void*)dstCnt, 0, (size_t)Nn * sizeof(int), stream);

    const int nb = (E + NT - 1) / NT;
    k_prep_hist<<<nb, NT, 0, stream>>>(Wr1, Wr2, Wr3, Wn1, Wn2, Wn3, wbf, ed, dstCnt, E);
    k_bsum <<<NB, 256, 0, stream>>>(dstCnt, blkSum, Nn);
    k_mid  <<<1, 64, 0, stream>>>(blkSum, blkOff, rowStart, NB, Nn, E);
    k_wout <<<NB, 256, 0, stream>>>(dstCnt, blkOff, rowStart, dstCursor, Nn);
    k_place<<<nb, NT, 0, stream>>>(et, ed, es, dstCursor, csrKey, E, Nn);

    k_dense<<<DGRID, NT, DSMEM_ELEMS * sizeof(__bf16), stream>>>(nf, br1, br2, br3, wbf, ca, Nn);
    k_node <<<(Nn + 127) / 128, NNT, NSMEM_ELEMS * sizeof(__bf16), stream>>>(
        nf, bn1, bn2, bn3, wbf, ca, rowStart, csrKey, out, Nn);
}